// Round 15
// baseline (2104.493 us; speedup 1.0000x reference)
//
#include <hip/hip_runtime.h>
#include <hip/hip_bf16.h>
#include <stdint.h>

#define D_MODEL 2048
#define D_FFN   8192
#define NTOK    8192
#define TOPK    256

typedef __bf16 bf16x8 __attribute__((ext_vector_type(8)));
typedef __bf16 bf16x4 __attribute__((ext_vector_type(4)));
typedef float  f32x4  __attribute__((ext_vector_type(4)));
typedef float  f32x16 __attribute__((ext_vector_type(16)));

// ---------------------------------------------------------------------------
// global -> LDS direct (16B per lane; LDS dest = wave-uniform base + lane*16)
// ---------------------------------------------------------------------------
__device__ inline void load_lds16(const void* g, void* l) {
    __builtin_amdgcn_global_load_lds((__attribute__((address_space(1))) void*)g,
                                     (__attribute__((address_space(3))) void*)l,
                                     16, 0, 0);
}

// ===========================================================================
// 256x256 bf16 GEMM — K-half slot ring, 4 slot-phases/iter, TWO barriers per
// slot-phase (r12-verified ring), MFMA = 32x32x16 (r15: 20% more FLOP/cyc
// than 16x16x32 per m119, half the instruction count).
// LESSON LEDGER:
//  r4/r5  — under waves_per_eu(2)'s 256-reg budget the 128-reg accumulator
//           spills: 3.8 GB scratch, 6.8% MfmaUtil.
//  r11    — sparse gather-refine (2.1 GB @1.3 TB/s) loses to dense MFMA
//           correction; compare gather-bytes/1.3TB/s vs extra-FLOPs/974TF.
//  r13    — the phase-OPEN barrier is load-bearing (phase-aligns the two
//           waves/SIMD). Removing it cost 7%. Do NOT remove.
// Fragments (32x32x16): A/B row = lane&31, k = (lane>>5)*8+e;
// C/D col = lane&31, row = (reg&3)+8*(reg>>2)+4*(lane>>5)  [m74/m101].
// Swizzle key (both sides, rule 21): key(r) = ((r>>1)^(r>>3))&3 — balanced:
// each 4-bank group serves exactly 8 accesses per b128 wave-read (minimum).
// Ring invariants (r8/r9): one A+B K-half staged per slot-phase landing 6
// phases before first read; vmcnt(4) at sp1/sp3 close (vm(0) last iter)
// retires exactly the two slots read next.
// ===========================================================================
template<int NSEG, int SEGK, int LDA, int LDB, int LDC, bool ATOMIC, bool OUTB16>
__global__ __attribute__((amdgpu_flat_work_group_size(512, 512),
                          amdgpu_waves_per_eu(2)))
void g256p(const __bf16* __restrict__ A0, const __bf16* __restrict__ A1,
           const __bf16* __restrict__ A2,
           const __bf16* __restrict__ B0, const __bf16* __restrict__ B1,
           const __bf16* __restrict__ B2,
           float* __restrict__ C)
{
    constexpr int KEXT = NSEG * SEGK;  // K extent per block
    constexpr int NH   = KEXT / 32;    // K-halves
    constexpr int NIT  = NH / 4;       // ring iterations

    __shared__ __align__(16) __bf16 sA[4][256][32];   // 64 KiB
    __shared__ __align__(16) __bf16 sB[4][256][32];   // 64 KiB

    const int tid  = threadIdx.x;
    const int lane = tid & 63;
    const int wid  = tid >> 6;            // 0..7
    const int mb   = blockIdx.y;
    const int nb   = blockIdx.x;

    const size_t zoff = (size_t)blockIdx.z * KEXT;   // k-split (gridDim.z>1 => NSEG==1)
    A0 += zoff; B0 += zoff;

    const int wm = (wid >> 2) * 128;      // wave A-rows [wm, wm+128)
    const int wn = (wid & 3) * 64;        // wave B-rows [wn, wn+64)
    const int l31 = lane & 31;
    const int lh  = lane >> 5;            // 0/1

    // read-side swizzle: chunk = ((ks<<1)|lh) ^ key(l31); byte = chunk<<4
    const int key = ((l31 >> 1) ^ (l31 >> 3)) & 3;
    const int sk0 = (lh ^ key) << 4;      // ks=0 byte offset; ks=1: sk0^32

    // staging-side (source pre-swizzle, same key family)
    const int cl   = lane & 3;
    const int sr0  = wid * 32 + (lane >> 2);
    const int skey = ((sr0 >> 1) ^ (sr0 >> 3)) & 3;
    const int cgel = (cl ^ skey) * 8;     // element offset pass0; pass1: ^16

    f32x16 acc[4][2] = {};

    auto STAGE = [&](int op, int J) {
        const int s = J & 3;
        int seg = 0, kin = J * 32;
        if (NSEG > 1) { seg = (J * 32) / SEGK; kin = J * 32 - seg * SEGK; }
        const __bf16* base = op
            ? ((NSEG == 1 || seg == 0) ? B0 : (seg == 1 ? B1 : B2))
            : ((NSEG == 1 || seg == 0) ? A0 : (seg == 1 ? A1 : A2));
        const int rowbase = (op ? nb : mb) * 256;
        const int ld = op ? LDB : LDA;
        char* ldsb = (char*)(op ? &sB[s][0][0] : &sA[s][0][0]) + wid * 2048;
        #pragma unroll
        for (int p = 0; p < 2; ++p) {
            const int r = sr0 + p * 16;
            load_lds16(base + (size_t)(rowbase + r) * ld + kin + (cgel ^ (p * 16)),
                       ldsb + p * 1024);
        }
    };

#define P_READ_B(s) { _Pragma("unroll") for (int n = 0; n < 2; ++n)            \
        _Pragma("unroll") for (int ks = 0; ks < 2; ++ks)                       \
            bfr[n * 2 + ks] = *(const bf16x8*)((const char*)                   \
                &sB[s][wn + n * 32 + l31][0] + (sk0 ^ (ks << 5))); }
#define P_READ_A(s, h) { _Pragma("unroll") for (int m = 0; m < 2; ++m)         \
        _Pragma("unroll") for (int ks = 0; ks < 2; ++ks)                       \
            af[m * 2 + ks] = *(const bf16x8*)((const char*)                    \
                &sA[s][wm + (h) * 64 + m * 32 + l31][0] + (sk0 ^ (ks << 5))); }
#define P_MFMA(h) { __builtin_amdgcn_s_setprio(1);                             \
    _Pragma("unroll") for (int ks = 0; ks < 2; ++ks)                           \
    _Pragma("unroll") for (int m = 0; m < 2; ++m)                              \
    _Pragma("unroll") for (int n = 0; n < 2; ++n)                              \
        acc[(h) * 2 + m][n] = __builtin_amdgcn_mfma_f32_32x32x16_bf16(         \
            af[m * 2 + ks], bfr[n * 2 + ks], acc[(h) * 2 + m][n], 0, 0, 0);    \
    __builtin_amdgcn_s_setprio(0); }
#define P_STAGE2(Joff) { const int J = J0 + (Joff);                            \
        if (J >= 4 && J < NH) { STAGE(0, J); STAGE(1, J); } }
#define P_BAR  __builtin_amdgcn_s_barrier()
#define P_LGKM { asm volatile("s_waitcnt lgkmcnt(0)" ::: "memory");            \
                 __builtin_amdgcn_sched_barrier(0); }
// r12 slot-phase: reads+stage, OPEN BAR (phase-aligns waves — r13 lesson),
// lgkm, MFMA h0, read A h1, lgkm, MFMA h1, [vm], CLOSE BAR.
#define SLOT_PHASE(sp, VM) {                                                   \
        P_READ_B(sp); P_READ_A(sp, 0);                                         \
        P_STAGE2(3 + (sp));                                                    \
        P_BAR; P_LGKM;                                                         \
        P_MFMA(0);                                                             \
        __builtin_amdgcn_sched_barrier(0);                                     \
        P_READ_A(sp, 1);                                                       \
        P_LGKM;                                                                \
        P_MFMA(1);                                                             \
        VM;                                                                    \
        P_BAR; }

    #pragma unroll
    for (int J = 0; J < 4; ++J) { STAGE(0, J); STAGE(1, J); }
    asm volatile("s_waitcnt vmcnt(0)" ::: "memory");
    P_BAR;

    for (int i = 0; i < NIT; ++i) {
        const int J0 = 4 * i;
        const bool last = (i == NIT - 1);
        bf16x8 af[4], bfr[4];

        SLOT_PHASE(0, );
        SLOT_PHASE(1,
            if (last) { asm volatile("s_waitcnt vmcnt(0)" ::: "memory"); }
            else      { asm volatile("s_waitcnt vmcnt(4)" ::: "memory"); });
        SLOT_PHASE(2, );
        SLOT_PHASE(3,
            if (last) { asm volatile("s_waitcnt vmcnt(0)" ::: "memory"); }
            else      { asm volatile("s_waitcnt vmcnt(4)" ::: "memory"); });
    }

#undef P_READ_B
#undef P_READ_A
#undef P_MFMA
#undef P_STAGE2
#undef P_BAR
#undef P_LGKM
#undef SLOT_PHASE

    // epilogue: 32x32 C/D layout col=lane&31, row=(j&3)+8*(j>>2)+4*(lane>>5)
    #pragma unroll
    for (int mi = 0; mi < 4; ++mi)
        #pragma unroll
        for (int ni = 0; ni < 2; ++ni)
            #pragma unroll
            for (int j = 0; j < 16; ++j) {
                const int r = mb * 256 + wm + mi * 32 +
                              (j & 3) + ((j >> 2) << 3) + (lh << 2);
                const int c = nb * 256 + wn + ni * 32 + l31;
                const float v = acc[mi][ni][j];
                if (ATOMIC)
                    unsafeAtomicAdd(&C[(size_t)r * LDC + c], v);
                else if (OUTB16)
                    ((__bf16*)C)[(size_t)r * LDC + c] = (__bf16)v;
                else
                    C[(size_t)r * LDC + c] = v;
            }
}

// ---------------------------------------------------------------------------
// x -> (x_hi, x_lo) bf16 split, elementwise
// ---------------------------------------------------------------------------
__global__ __launch_bounds__(256)
void split_convert(const float* __restrict__ in, __bf16* __restrict__ hi,
                   __bf16* __restrict__ lo, int n4)
{
    const int i = blockIdx.x * 256 + threadIdx.x;
    if (i >= n4) return;
    const float4 v = ((const float4*)in)[i];
    float f[4] = {v.x, v.y, v.z, v.w};
    bf16x4 h, l;
    #pragma unroll
    for (int j = 0; j < 4; ++j) {
        __bf16 hb = (__bf16)f[j];
        h[j] = hb;
        l[j] = (__bf16)(f[j] - (float)hb);
    }
    ((bf16x4*)hi)[i] = h;
    ((bf16x4*)lo)[i] = l;
}

// ---------------------------------------------------------------------------
// fp32 [R][C] -> bf16 transposed [C][R] (optionally hi+lo split)
// ---------------------------------------------------------------------------
template<bool SPLIT>
__global__ __launch_bounds__(256)
void transpose_bf16(const float* __restrict__ in, __bf16* __restrict__ outHi,
                    __bf16* __restrict__ outLo, int R, int C)
{
    __shared__ float tile[32][33];
    const int bx = blockIdx.x * 32;
    const int by = blockIdx.y * 32;
    const int tx = threadIdx.x & 31;
    const int ty = threadIdx.x >> 5;
    #pragma unroll
    for (int i = 0; i < 4; ++i)
        tile[ty + 8 * i][tx] = in[(size_t)(by + ty + 8 * i) * C + (bx + tx)];
    __syncthreads();
    #pragma unroll
    for (int i = 0; i < 4; ++i) {
        const float v = tile[tx][ty + 8 * i];
        const size_t o = (size_t)(bx + ty + 8 * i) * R + (by + tx);
        const __bf16 h = (__bf16)v;
        outHi[o] = h;
        if (SPLIT) outLo[o] = (__bf16)(v - (float)h);
    }
}

// ---------------------------------------------------------------------------
// exact top-256 per row of G[rows][D_FFN] fp32 (3-seg GEMM, G err ~1e-6):
// radix-select pivot, then fp64-exact arbitration of the ambiguous boundary
// (|g - vT| <= EPS) using the ORIGINAL fp32 x row and w_gate columns.
// Proven r3-r9/r12/r14. (r11: dense correction GEMM beats gather-refine.)
// ---------------------------------------------------------------------------
#define TK_EPS 3e-5f
#define TK_MAXA 64

__global__ __launch_bounds__(256)
void topk256(const float* __restrict__ G, const float* __restrict__ xblk,
             const float* __restrict__ wgate,
             int* __restrict__ idxOut, float* __restrict__ gkOut)
{
    const int row = blockIdx.x;
    const int t = threadIdx.x;
    const int lane = t & 63;
    const int wid  = t >> 6;

    __shared__ unsigned keys[D_FFN];
    __shared__ float    xr[D_MODEL];
    __shared__ unsigned hist[256];
    __shared__ unsigned scanb[256];
    __shared__ int      sIdx[TOPK];
    __shared__ float    sVal[TOPK];
    __shared__ int      ambIdx[TK_MAXA];
    __shared__ double   ambVal[TK_MAXA];
    __shared__ double   redW[4];
    __shared__ unsigned sh_bin, sh_above, sh_nc, sh_na, sh_fill;

    const float* g = G + (size_t)row * D_FFN;
    const float* xrow = xblk + (size_t)row * D_MODEL;
    for (int i = t; i < D_FFN; i += 256) {
        const unsigned u = __float_as_uint(g[i]);
        keys[i] = (u & 0x80000000u) ? ~u : (u | 0x80000000u);
    }
    for (int i = t; i < D_MODEL; i += 256) xr[i] = xrow[i];
    if (t == 0) { sh_nc = 0; sh_na = 0; sh_fill = 0; }
    __syncthreads();

    unsigned prefix = 0, pmask = 0;
    int remaining = TOPK;
    for (int shift = 24; shift >= 0; shift -= 8) {
        hist[t] = 0;
        __syncthreads();
        for (int i = t; i < D_FFN; i += 256) {
            const unsigned k = keys[i];
            if ((k & pmask) == prefix) atomicAdd(&hist[(k >> shift) & 255u], 1u);
        }
        __syncthreads();
        scanb[t] = hist[t];
        __syncthreads();
        for (int off = 1; off < 256; off <<= 1) {
            const unsigned add = (t + off < 256) ? scanb[t + off] : 0u;
            __syncthreads();
            scanb[t] += add;
            __syncthreads();
        }
        const unsigned above = (t == 255) ? 0u : scanb[t + 1];
        if (scanb[t] >= (unsigned)remaining && above < (unsigned)remaining) {
            sh_bin = (unsigned)t;
            sh_above = above;
        }
        __syncthreads();
        prefix |= sh_bin << shift;
        pmask  |= 0xFFu << shift;
        remaining -= (int)sh_above;
        __syncthreads();
    }
    const unsigned Tkey = prefix;
    const float vT = __uint_as_float((Tkey & 0x80000000u) ? (Tkey & 0x7FFFFFFFu) : ~Tkey);

    for (int i = t; i < D_FFN; i += 256) {
        const unsigned k = keys[i];
        const float f = __uint_as_float((k & 0x80000000u) ? (k & 0x7FFFFFFFu) : ~k);
        if (f > vT + TK_EPS) {
            const unsigned p = atomicAdd(&sh_nc, 1u);
            sIdx[p] = i;
            sVal[p] = f;
        } else if (f >= vT - TK_EPS) {
            const unsigned p = atomicAdd(&sh_na, 1u);
            if (p < TK_MAXA) ambIdx[p] = i;
        }
    }
    __syncthreads();
    const int nc = (int)sh_nc;
    const int na = min((int)sh_na, TK_MAXA);
    const int need = TOPK - nc;

    if (need >= na) {
        if (t < na) {
            const unsigned k = keys[ambIdx[t]];
            sIdx[nc + t] = ambIdx[t];
            sVal[nc + t] = __uint_as_float((k & 0x80000000u) ? (k & 0x7FFFFFFFu) : ~k);
        }
        __syncthreads();
    } else {
        for (int j = 0; j < na; ++j) {
            const int col = ambIdx[j];
            double p = 0.0;
            for (int k = t; k < D_MODEL; k += 256)
                p += (double)xr[k] * (double)wgate[(size_t)k * D_FFN + col];
            #pragma unroll
            for (int o = 32; o > 0; o >>= 1) p += __shfl_xor(p, o, 64);
            if (lane == 0) redW[wid] = p;
            __syncthreads();
            if (t == 0) ambVal[j] = (redW[0] + redW[1]) + (redW[2] + redW[3]);
            __syncthreads();
        }
        if (t < na) {
            const double v = ambVal[t];
            const int    c = ambIdx[t];
            int r = 0;
            for (int j = 0; j < na; ++j) {
                const double vj = ambVal[j];
                if (vj > v || (vj == v && ambIdx[j] < c)) r++;
            }
            if (r < need) {
                const unsigned p = atomicAdd(&sh_fill, 1u);
                sIdx[nc + p] = c;
                sVal[nc + p] = (float)v;
            }
        }
        __syncthreads();
    }

    idxOut[(size_t)row * TOPK + t] = sIdx[t];
    gkOut[(size_t)row * TOPK + t] = sVal[t];
}

// ---------------------------------------------------------------------------
// per-row: zero the Zd row, then scatter z = silu(gk)*u at the 256 selected
// columns (U stored bf16). Replaces zero_buf + z_fused (launch fusion).
// ---------------------------------------------------------------------------
__global__ __launch_bounds__(256)
void z_zero_scatter(const int* __restrict__ idx, const float* __restrict__ gk,
                    const __bf16* __restrict__ Ub, __bf16* __restrict__ Zd)
{
    const int r = blockIdx.x, t = threadIdx.x;
    bf16x8 zv = {};
    bf16x8* rowv = (bf16x8*)(Zd + (size_t)r * D_FFN);
    #pragma unroll
    for (int j = 0; j < 4; ++j) rowv[j * 256 + t] = zv;   // 8192 bf16 zeroed
    __syncthreads();
    const int p = r * TOPK + t;
    const int c = idx[p];
    const float g = gk[p];
    const float u = (float)Ub[(size_t)r * D_FFN + c];
    const float s = g / (1.0f + __expf(-g));
    Zd[(size_t)r * D_FFN + c] = (__bf16)(s * u);
}

__global__ __launch_bounds__(256)
void zero_buf(float4* __restrict__ p, int n)
{
    int i = blockIdx.x * 256 + threadIdx.x;
    const int stride = gridDim.x * 256;
    for (; i < n; i += stride) p[i] = make_float4(0.f, 0.f, 0.f, 0.f);
}

// ---------------------------------------------------------------------------
extern "C" void kernel_launch(void* const* d_in, const int* in_sizes, int n_in,
                              void* d_out, int out_size, void* d_ws, size_t ws_size,
                              hipStream_t stream)
{
    const float* x  = (const float*)d_in[0];
    const float* wg = (const float*)d_in[1];
    const float* wu = (const float*)d_in[2];
    const float* wd = (const float*)d_in[3];
    float* out = (float*)d_out;

    const size_t SZ_XB = (size_t)NTOK * D_MODEL * 2;    // 32 MiB
    const size_t SZ_WB = (size_t)D_FFN * D_MODEL * 2;   // 32 MiB
    const size_t SZ_IK = (size_t)NTOK * TOPK * 4;       // 8 MiB
    const size_t SZ_ZD = (size_t)NTOK * D_FFN * 2;      // 128 MiB (full Zd)
    char* ws = (char*)d_ws;
    size_t off = 0;
    auto alloc = [&](size_t bytes) -> char* {
        char* p = ws + off;
        off += (bytes + 255) & ~(size_t)255;
        return p;
    };
    __bf16* x_hi  = (__bf16*)alloc(SZ_XB);
    __bf16* wT_a  = (__bf16*)alloc(SZ_WB);   // wgT_hi, then wuT
    __bf16* wT_b  = (__bf16*)alloc(SZ_WB);   // wgT_lo, then wdT
    int*    idx   = (int*)  alloc(SZ_IK);
    float*  gk    = (float*)alloc(SZ_IK);

    // row-block size: Eblk (fp32 RB x D_FFN) + x_lo must fit
    int RB = 2048;
    while (RB > 256 && off + (size_t)RB * D_FFN * 4 + SZ_XB > ws_size) RB >>= 1;
    float*  Eblk = (float*)alloc((size_t)RB * D_FFN * 4);  // G fp32, then U bf16
    const size_t xlo_off = off;
    __bf16* x_lo = (__bf16*)alloc(SZ_XB);
    // full-Zd fast path: Zd overlays x_lo (dead after G phase) + extension
    const bool fullZd = (RB == 2048) && (xlo_off + SZ_ZD <= ws_size);
    __bf16* Zd_full = (__bf16*)(ws + xlo_off);
    __bf16* Zdb     = x_lo;                                // fallback per-rb Zd
    __bf16* Ub      = (__bf16*)Eblk;                       // U stored bf16
    const int NRB = NTOK / RB;

    // 1) operand conversions for the G phase
    split_convert<<<(NTOK * D_MODEL / 4 + 255) / 256, 256, 0, stream>>>(
        x, x_hi, x_lo, NTOK * D_MODEL / 4);
    transpose_bf16<true><<<dim3(D_FFN / 32, D_MODEL / 32), 256, 0, stream>>>(
        wg, wT_a, wT_b, D_MODEL, D_FFN);   // wgT_hi, wgT_lo

    // 2) G phase per row-block: 3-seg stacked-K bf16 GEMM -> exact topk
    for (int rb = 0; rb < NRB; ++rb) {
        const size_t aoff = (size_t)rb * RB * D_MODEL;
        g256p<3, D_MODEL, D_MODEL, D_MODEL, D_FFN, false, false>
            <<<dim3(D_FFN / 256, RB / 256, 1), 512, 0, stream>>>(
                x_hi + aoff, x_lo + aoff, x_hi + aoff,
                wT_a, wT_a, wT_b, Eblk);
        topk256<<<RB, 256, 0, stream>>>(
            Eblk, x + aoff, wg,
            idx + (size_t)rb * RB * TOPK, gk + (size_t)rb * RB * TOPK);
    }

    // 3) weight conversions for U/down phases (wg copies dead now)
    transpose_bf16<false><<<dim3(D_FFN / 32, D_MODEL / 32), 256, 0, stream>>>(
        wu, wT_a, nullptr, D_MODEL, D_FFN);   // wuT [D_FFN][D_MODEL]
    transpose_bf16<false><<<dim3(D_MODEL / 32, D_FFN / 32), 256, 0, stream>>>(
        wd, wT_b, nullptr, D_FFN, D_MODEL);   // wdT [D_MODEL][D_FFN]

    if (fullZd) {
        // 4a) U (bf16 out) -> fused zero+scatter into full Zd, per row-block
        for (int rb = 0; rb < NRB; ++rb) {
            const size_t aoff = (size_t)rb * RB * D_MODEL;
            g256p<1, D_MODEL, D_MODEL, D_MODEL, D_FFN, false, true>
                <<<dim3(D_FFN / 256, RB / 256, 1), 512, 0, stream>>>(
                    x_hi + aoff, nullptr, nullptr, wT_a, nullptr, nullptr, Eblk);
            z_zero_scatter<<<RB, 256, 0, stream>>>(
                idx + (size_t)rb * RB * TOPK, gk + (size_t)rb * RB * TOPK,
                Ub, Zd_full + (size_t)rb * RB * D_FFN);
        }
        // 5a) single full-K down projection, no atomics
        g256p<1, D_FFN, D_FFN, D_FFN, D_MODEL, false, false>
            <<<dim3(D_MODEL / 256, NTOK / 256, 1), 512, 0, stream>>>(
                Zd_full, nullptr, nullptr, wT_b, nullptr, nullptr, out);
    } else {
        // 4b) fallback (r12-proven): per-rb Zd + k-split atomic down
        zero_buf<<<4096, 256, 0, stream>>>(
            (float4*)out, (int)((size_t)NTOK * D_MODEL * 4 / 16));
        for (int rb = 0; rb < NRB; ++rb) {
            const size_t aoff = (size_t)rb * RB * D_MODEL;
            g256p<1, D_MODEL, D_MODEL, D_MODEL, D_FFN, false, true>
                <<<dim3(D_FFN / 256, RB / 256, 1), 512, 0, stream>>>(
                    x_hi + aoff, nullptr, nullptr, wT_a, nullptr, nullptr, Eblk);
            z_zero_scatter<<<RB, 256, 0, stream>>>(
                idx + (size_t)rb * RB * TOPK, gk + (size_t)rb * RB * TOPK,
                Ub, Zdb);
            g256p<1, D_MODEL, D_FFN, D_FFN, D_MODEL, true, false>
                <<<dim3(D_MODEL / 256, RB / 256, D_FFN / D_MODEL), 512, 0, stream>>>(
                    Zdb, nullptr, nullptr, wT_b, nullptr, nullptr, out + aoff);
        }
    }
}

// Round 16
// 2101.911 us; speedup vs baseline: 1.0012x; 1.0012x over previous
//
#include <hip/hip_runtime.h>
#include <hip/hip_bf16.h>
#include <stdint.h>

#define D_MODEL 2048
#define D_FFN   8192
#define NTOK    8192
#define TOPK    256

typedef __bf16 bf16x8 __attribute__((ext_vector_type(8)));
typedef __bf16 bf16x4 __attribute__((ext_vector_type(4)));
typedef float  f32x4  __attribute__((ext_vector_type(4)));
typedef float  f32x16 __attribute__((ext_vector_type(16)));

// ---------------------------------------------------------------------------
// global -> LDS direct (16B per lane; LDS dest = wave-uniform base + lane*16)
// ---------------------------------------------------------------------------
__device__ inline void load_lds16(const void* g, void* l) {
    __builtin_amdgcn_global_load_lds((__attribute__((address_space(1))) void*)g,
                                     (__attribute__((address_space(3))) void*)l,
                                     16, 0, 0);
}

// ===========================================================================
// 256x256 bf16 GEMM — K-half slot ring (r12 pipeline), MFMA = 32x32x16.
// LESSON LEDGER:
//  r4/r5  — under waves_per_eu(2)'s 256-reg budget the accumulator spills.
//  r11    — sparse gather-refine loses to dense MFMA correction.
//  r13    — the phase-OPEN barrier is load-bearing. Do NOT remove.
//  r15    — b128 LDS reads are processed in cycles of lane quads
//           {4i..4i+3} U {32+4i..+3} (inferred: r15's lh^1 chunk offset gave
//           EXACTLY +4 cyc/b128 = 2-way every cycle; 16x16's q-offset-2 gave
//           0). Conflict-free requires lanes l and l+32 to differ in chunk
//           BIT 1 -> chunk = key(r) ^ (lh<<1) ^ ks, key(r)=((r>>1)^(r>>3))&3.
// Fragments (32x32x16): A/B row = lane&31, k = (lane>>5)*8+e;
// C/D col = lane&31, row = (reg&3)+8*(reg>>2)+4*(lane>>5)  [m74/m101;
// absmax-verified r15].
// Staging stores logical chunk cl at phys = key ^ swapbits(cl); lane l
// (phys chunk l&3) fetches global elem 8*swapbits((l&3)^key); pass1 ^8.
// Ring invariants (r8/r9): one A+B K-half staged per slot-phase landing 6
// phases before first read; vmcnt(4) at sp1/sp3 close (vm(0) last iter).
// ===========================================================================
template<int NSEG, int SEGK, int LDA, int LDB, int LDC, bool ATOMIC, bool OUTB16>
__global__ __attribute__((amdgpu_flat_work_group_size(512, 512),
                          amdgpu_waves_per_eu(2)))
void g256p(const __bf16* __restrict__ A0, const __bf16* __restrict__ A1,
           const __bf16* __restrict__ A2,
           const __bf16* __restrict__ B0, const __bf16* __restrict__ B1,
           const __bf16* __restrict__ B2,
           float* __restrict__ C)
{
    constexpr int KEXT = NSEG * SEGK;  // K extent per block
    constexpr int NH   = KEXT / 32;    // K-halves
    constexpr int NIT  = NH / 4;       // ring iterations

    __shared__ __align__(16) __bf16 sA[4][256][32];   // 64 KiB
    __shared__ __align__(16) __bf16 sB[4][256][32];   // 64 KiB

    const int tid  = threadIdx.x;
    const int lane = tid & 63;
    const int wid  = tid >> 6;            // 0..7
    const int mb   = blockIdx.y;
    const int nb   = blockIdx.x;

    const size_t zoff = (size_t)blockIdx.z * KEXT;   // k-split (gridDim.z>1 => NSEG==1)
    A0 += zoff; B0 += zoff;

    const int wm = (wid >> 2) * 128;      // wave A-rows [wm, wm+128)
    const int wn = (wid & 3) * 64;        // wave B-rows [wn, wn+64)
    const int l31 = lane & 31;
    const int lh  = lane >> 5;            // 0/1

    // read-side swizzle (r16): chunk = key(r) ^ (lh<<1) ^ ks
    const int key = ((l31 >> 1) ^ (l31 >> 3)) & 3;
    const int sk0 = ((key ^ (lh << 1)) << 4);   // ks=0 byte offset; ks=1: ^16

    // staging-side: lane l holds phys chunk (l&3); fetch logical chunk
    // swapbits((l&3) ^ key(sr0)); pass1: logical ^1 (elem offset ^8)
    const int cl   = lane & 3;
    const int sr0  = wid * 32 + (lane >> 2);
    const int skey = ((sr0 >> 1) ^ (sr0 >> 3)) & 3;
    const int pk   = cl ^ skey;
    const int cgel = (((pk & 1) << 1) | ((pk >> 1) & 1)) * 8;  // swapbits*8

    f32x16 acc[4][2] = {};

    auto STAGE = [&](int op, int J) {
        const int s = J & 3;
        int seg = 0, kin = J * 32;
        if (NSEG > 1) { seg = (J * 32) / SEGK; kin = J * 32 - seg * SEGK; }
        const __bf16* base = op
            ? ((NSEG == 1 || seg == 0) ? B0 : (seg == 1 ? B1 : B2))
            : ((NSEG == 1 || seg == 0) ? A0 : (seg == 1 ? A1 : A2));
        const int rowbase = (op ? nb : mb) * 256;
        const int ld = op ? LDB : LDA;
        char* ldsb = (char*)(op ? &sB[s][0][0] : &sA[s][0][0]) + wid * 2048;
        #pragma unroll
        for (int p = 0; p < 2; ++p) {
            const int r = sr0 + p * 16;
            load_lds16(base + (size_t)(rowbase + r) * ld + kin + (cgel ^ (p * 8)),
                       ldsb + p * 1024);
        }
    };

#define P_READ_B(s) { _Pragma("unroll") for (int n = 0; n < 2; ++n)            \
        _Pragma("unroll") for (int ks = 0; ks < 2; ++ks)                       \
            bfr[n * 2 + ks] = *(const bf16x8*)((const char*)                   \
                &sB[s][wn + n * 32 + l31][0] + (sk0 ^ (ks << 4))); }
#define P_READ_A(s, h) { _Pragma("unroll") for (int m = 0; m < 2; ++m)         \
        _Pragma("unroll") for (int ks = 0; ks < 2; ++ks)                       \
            af[m * 2 + ks] = *(const bf16x8*)((const char*)                    \
                &sA[s][wm + (h) * 64 + m * 32 + l31][0] + (sk0 ^ (ks << 4))); }
#define P_MFMA(h) { __builtin_amdgcn_s_setprio(1);                             \
    _Pragma("unroll") for (int ks = 0; ks < 2; ++ks)                           \
    _Pragma("unroll") for (int m = 0; m < 2; ++m)                              \
    _Pragma("unroll") for (int n = 0; n < 2; ++n)                              \
        acc[(h) * 2 + m][n] = __builtin_amdgcn_mfma_f32_32x32x16_bf16(         \
            af[m * 2 + ks], bfr[n * 2 + ks], acc[(h) * 2 + m][n], 0, 0, 0);    \
    __builtin_amdgcn_s_setprio(0); }
#define P_STAGE2(Joff) { const int J = J0 + (Joff);                            \
        if (J >= 4 && J < NH) { STAGE(0, J); STAGE(1, J); } }
#define P_BAR  __builtin_amdgcn_s_barrier()
#define P_LGKM { asm volatile("s_waitcnt lgkmcnt(0)" ::: "memory");            \
                 __builtin_amdgcn_sched_barrier(0); }
// r12 slot-phase: reads+stage, OPEN BAR (phase-aligns waves — r13 lesson),
// lgkm, MFMA h0, read A h1, lgkm, MFMA h1, [vm], CLOSE BAR.
#define SLOT_PHASE(sp, VM) {                                                   \
        P_READ_B(sp); P_READ_A(sp, 0);                                         \
        P_STAGE2(3 + (sp));                                                    \
        P_BAR; P_LGKM;                                                         \
        P_MFMA(0);                                                             \
        __builtin_amdgcn_sched_barrier(0);                                     \
        P_READ_A(sp, 1);                                                       \
        P_LGKM;                                                                \
        P_MFMA(1);                                                             \
        VM;                                                                    \
        P_BAR; }

    #pragma unroll
    for (int J = 0; J < 4; ++J) { STAGE(0, J); STAGE(1, J); }
    asm volatile("s_waitcnt vmcnt(0)" ::: "memory");
    P_BAR;

    for (int i = 0; i < NIT; ++i) {
        const int J0 = 4 * i;
        const bool last = (i == NIT - 1);
        bf16x8 af[4], bfr[4];

        SLOT_PHASE(0, );
        SLOT_PHASE(1,
            if (last) { asm volatile("s_waitcnt vmcnt(0)" ::: "memory"); }
            else      { asm volatile("s_waitcnt vmcnt(4)" ::: "memory"); });
        SLOT_PHASE(2, );
        SLOT_PHASE(3,
            if (last) { asm volatile("s_waitcnt vmcnt(0)" ::: "memory"); }
            else      { asm volatile("s_waitcnt vmcnt(4)" ::: "memory"); });
    }

#undef P_READ_B
#undef P_READ_A
#undef P_MFMA
#undef P_STAGE2
#undef P_BAR
#undef P_LGKM
#undef SLOT_PHASE

    // epilogue: 32x32 C/D layout col=lane&31, row=(j&3)+8*(j>>2)+4*(lane>>5)
    #pragma unroll
    for (int mi = 0; mi < 4; ++mi)
        #pragma unroll
        for (int ni = 0; ni < 2; ++ni)
            #pragma unroll
            for (int j = 0; j < 16; ++j) {
                const int r = mb * 256 + wm + mi * 32 +
                              (j & 3) + ((j >> 2) << 3) + (lh << 2);
                const int c = nb * 256 + wn + ni * 32 + l31;
                const float v = acc[mi][ni][j];
                if (ATOMIC)
                    unsafeAtomicAdd(&C[(size_t)r * LDC + c], v);
                else if (OUTB16)
                    ((__bf16*)C)[(size_t)r * LDC + c] = (__bf16)v;
                else
                    C[(size_t)r * LDC + c] = v;
            }
}

// ---------------------------------------------------------------------------
// x -> (x_hi, x_lo) bf16 split, elementwise
// ---------------------------------------------------------------------------
__global__ __launch_bounds__(256)
void split_convert(const float* __restrict__ in, __bf16* __restrict__ hi,
                   __bf16* __restrict__ lo, int n4)
{
    const int i = blockIdx.x * 256 + threadIdx.x;
    if (i >= n4) return;
    const float4 v = ((const float4*)in)[i];
    float f[4] = {v.x, v.y, v.z, v.w};
    bf16x4 h, l;
    #pragma unroll
    for (int j = 0; j < 4; ++j) {
        __bf16 hb = (__bf16)f[j];
        h[j] = hb;
        l[j] = (__bf16)(f[j] - (float)hb);
    }
    ((bf16x4*)hi)[i] = h;
    ((bf16x4*)lo)[i] = l;
}

// ---------------------------------------------------------------------------
// fp32 [R][C] -> bf16 transposed [C][R] (optionally hi+lo split)
// ---------------------------------------------------------------------------
template<bool SPLIT>
__global__ __launch_bounds__(256)
void transpose_bf16(const float* __restrict__ in, __bf16* __restrict__ outHi,
                    __bf16* __restrict__ outLo, int R, int C)
{
    __shared__ float tile[32][33];
    const int bx = blockIdx.x * 32;
    const int by = blockIdx.y * 32;
    const int tx = threadIdx.x & 31;
    const int ty = threadIdx.x >> 5;
    #pragma unroll
    for (int i = 0; i < 4; ++i)
        tile[ty + 8 * i][tx] = in[(size_t)(by + ty + 8 * i) * C + (bx + tx)];
    __syncthreads();
    #pragma unroll
    for (int i = 0; i < 4; ++i) {
        const float v = tile[tx][ty + 8 * i];
        const size_t o = (size_t)(bx + ty + 8 * i) * R + (by + tx);
        const __bf16 h = (__bf16)v;
        outHi[o] = h;
        if (SPLIT) outLo[o] = (__bf16)(v - (float)h);
    }
}

// ---------------------------------------------------------------------------
// exact top-256 per row of G[rows][D_FFN] fp32 (3-seg GEMM, G err ~1e-6):
// radix-select pivot, then fp64-exact arbitration of the ambiguous boundary
// (|g - vT| <= EPS) using the ORIGINAL fp32 x row and w_gate columns.
// Proven r3-r9/r12/r14. (r11: dense correction GEMM beats gather-refine.)
// ---------------------------------------------------------------------------
#define TK_EPS 3e-5f
#define TK_MAXA 64

__global__ __launch_bounds__(256)
void topk256(const float* __restrict__ G, const float* __restrict__ xblk,
             const float* __restrict__ wgate,
             int* __restrict__ idxOut, float* __restrict__ gkOut)
{
    const int row = blockIdx.x;
    const int t = threadIdx.x;
    const int lane = t & 63;
    const int wid  = t >> 6;

    __shared__ unsigned keys[D_FFN];
    __shared__ float    xr[D_MODEL];
    __shared__ unsigned hist[256];
    __shared__ unsigned scanb[256];
    __shared__ int      sIdx[TOPK];
    __shared__ float    sVal[TOPK];
    __shared__ int      ambIdx[TK_MAXA];
    __shared__ double   ambVal[TK_MAXA];
    __shared__ double   redW[4];
    __shared__ unsigned sh_bin, sh_above, sh_nc, sh_na, sh_fill;

    const float* g = G + (size_t)row * D_FFN;
    const float* xrow = xblk + (size_t)row * D_MODEL;
    for (int i = t; i < D_FFN; i += 256) {
        const unsigned u = __float_as_uint(g[i]);
        keys[i] = (u & 0x80000000u) ? ~u : (u | 0x80000000u);
    }
    for (int i = t; i < D_MODEL; i += 256) xr[i] = xrow[i];
    if (t == 0) { sh_nc = 0; sh_na = 0; sh_fill = 0; }
    __syncthreads();

    unsigned prefix = 0, pmask = 0;
    int remaining = TOPK;
    for (int shift = 24; shift >= 0; shift -= 8) {
        hist[t] = 0;
        __syncthreads();
        for (int i = t; i < D_FFN; i += 256) {
            const unsigned k = keys[i];
            if ((k & pmask) == prefix) atomicAdd(&hist[(k >> shift) & 255u], 1u);
        }
        __syncthreads();
        scanb[t] = hist[t];
        __syncthreads();
        for (int off = 1; off < 256; off <<= 1) {
            const unsigned add = (t + off < 256) ? scanb[t + off] : 0u;
            __syncthreads();
            scanb[t] += add;
            __syncthreads();
        }
        const unsigned above = (t == 255) ? 0u : scanb[t + 1];
        if (scanb[t] >= (unsigned)remaining && above < (unsigned)remaining) {
            sh_bin = (unsigned)t;
            sh_above = above;
        }
        __syncthreads();
        prefix |= sh_bin << shift;
        pmask  |= 0xFFu << shift;
        remaining -= (int)sh_above;
        __syncthreads();
    }
    const unsigned Tkey = prefix;
    const float vT = __uint_as_float((Tkey & 0x80000000u) ? (Tkey & 0x7FFFFFFFu) : ~Tkey);

    for (int i = t; i < D_FFN; i += 256) {
        const unsigned k = keys[i];
        const float f = __uint_as_float((k & 0x80000000u) ? (k & 0x7FFFFFFFu) : ~k);
        if (f > vT + TK_EPS) {
            const unsigned p = atomicAdd(&sh_nc, 1u);
            sIdx[p] = i;
            sVal[p] = f;
        } else if (f >= vT - TK_EPS) {
            const unsigned p = atomicAdd(&sh_na, 1u);
            if (p < TK_MAXA) ambIdx[p] = i;
        }
    }
    __syncthreads();
    const int nc = (int)sh_nc;
    const int na = min((int)sh_na, TK_MAXA);
    const int need = TOPK - nc;

    if (need >= na) {
        if (t < na) {
            const unsigned k = keys[ambIdx[t]];
            sIdx[nc + t] = ambIdx[t];
            sVal[nc + t] = __uint_as_float((k & 0x80000000u) ? (k & 0x7FFFFFFFu) : ~k);
        }
        __syncthreads();
    } else {
        for (int j = 0; j < na; ++j) {
            const int col = ambIdx[j];
            double p = 0.0;
            for (int k = t; k < D_MODEL; k += 256)
                p += (double)xr[k] * (double)wgate[(size_t)k * D_FFN + col];
            #pragma unroll
            for (int o = 32; o > 0; o >>= 1) p += __shfl_xor(p, o, 64);
            if (lane == 0) redW[wid] = p;
            __syncthreads();
            if (t == 0) ambVal[j] = (redW[0] + redW[1]) + (redW[2] + redW[3]);
            __syncthreads();
        }
        if (t < na) {
            const double v = ambVal[t];
            const int    c = ambIdx[t];
            int r = 0;
            for (int j = 0; j < na; ++j) {
                const double vj = ambVal[j];
                if (vj > v || (vj == v && ambIdx[j] < c)) r++;
            }
            if (r < need) {
                const unsigned p = atomicAdd(&sh_fill, 1u);
                sIdx[nc + p] = c;
                sVal[nc + p] = (float)v;
            }
        }
        __syncthreads();
    }

    idxOut[(size_t)row * TOPK + t] = sIdx[t];
    gkOut[(size_t)row * TOPK + t] = sVal[t];
}

// ---------------------------------------------------------------------------
// per-row: zero the Zd row, then scatter z = silu(gk)*u at the 256 selected
// columns (U stored bf16). Replaces zero_buf + z_fused (launch fusion).
// ---------------------------------------------------------------------------
__global__ __launch_bounds__(256)
void z_zero_scatter(const int* __restrict__ idx, const float* __restrict__ gk,
                    const __bf16* __restrict__ Ub, __bf16* __restrict__ Zd)
{
    const int r = blockIdx.x, t = threadIdx.x;
    bf16x8 zv = {};
    bf16x8* rowv = (bf16x8*)(Zd + (size_t)r * D_FFN);
    #pragma unroll
    for (int j = 0; j < 4; ++j) rowv[j * 256 + t] = zv;   // 8192 bf16 zeroed
    __syncthreads();
    const int p = r * TOPK + t;
    const int c = idx[p];
    const float g = gk[p];
    const float u = (float)Ub[(size_t)r * D_FFN + c];
    const float s = g / (1.0f + __expf(-g));
    Zd[(size_t)r * D_FFN + c] = (__bf16)(s * u);
}

__global__ __launch_bounds__(256)
void zero_buf(float4* __restrict__ p, int n)
{
    int i = blockIdx.x * 256 + threadIdx.x;
    const int stride = gridDim.x * 256;
    for (; i < n; i += stride) p[i] = make_float4(0.f, 0.f, 0.f, 0.f);
}

// ---------------------------------------------------------------------------
extern "C" void kernel_launch(void* const* d_in, const int* in_sizes, int n_in,
                              void* d_out, int out_size, void* d_ws, size_t ws_size,
                              hipStream_t stream)
{
    const float* x  = (const float*)d_in[0];
    const float* wg = (const float*)d_in[1];
    const float* wu = (const float*)d_in[2];
    const float* wd = (const float*)d_in[3];
    float* out = (float*)d_out;

    const size_t SZ_XB = (size_t)NTOK * D_MODEL * 2;    // 32 MiB
    const size_t SZ_WB = (size_t)D_FFN * D_MODEL * 2;   // 32 MiB
    const size_t SZ_IK = (size_t)NTOK * TOPK * 4;       // 8 MiB
    const size_t SZ_ZD = (size_t)NTOK * D_FFN * 2;      // 128 MiB (full Zd)
    char* ws = (char*)d_ws;
    size_t off = 0;
    auto alloc = [&](size_t bytes) -> char* {
        char* p = ws + off;
        off += (bytes + 255) & ~(size_t)255;
        return p;
    };
    __bf16* x_hi  = (__bf16*)alloc(SZ_XB);
    __bf16* wT_a  = (__bf16*)alloc(SZ_WB);   // wgT_hi, then wuT
    __bf16* wT_b  = (__bf16*)alloc(SZ_WB);   // wgT_lo, then wdT
    int*    idx   = (int*)  alloc(SZ_IK);
    float*  gk    = (float*)alloc(SZ_IK);

    // row-block size: Eblk (fp32 RB x D_FFN) + x_lo must fit
    int RB = 2048;
    while (RB > 256 && off + (size_t)RB * D_FFN * 4 + SZ_XB > ws_size) RB >>= 1;
    float*  Eblk = (float*)alloc((size_t)RB * D_FFN * 4);  // G fp32, then U bf16
    const size_t xlo_off = off;
    __bf16* x_lo = (__bf16*)alloc(SZ_XB);
    // full-Zd fast path: Zd overlays x_lo (dead after G phase) + extension
    const bool fullZd = (RB == 2048) && (xlo_off + SZ_ZD <= ws_size);
    __bf16* Zd_full = (__bf16*)(ws + xlo_off);
    __bf16* Zdb     = x_lo;                                // fallback per-rb Zd
    __bf16* Ub      = (__bf16*)Eblk;                       // U stored bf16
    const int NRB = NTOK / RB;

    // 1) operand conversions for the G phase
    split_convert<<<(NTOK * D_MODEL / 4 + 255) / 256, 256, 0, stream>>>(
        x, x_hi, x_lo, NTOK * D_MODEL / 4);
    transpose_bf16<true><<<dim3(D_FFN / 32, D_MODEL / 32), 256, 0, stream>>>(
        wg, wT_a, wT_b, D_MODEL, D_FFN);   // wgT_hi, wgT_lo

    // 2) G phase per row-block: 3-seg stacked-K bf16 GEMM -> exact topk
    for (int rb = 0; rb < NRB; ++rb) {
        const size_t aoff = (size_t)rb * RB * D_MODEL;
        g256p<3, D_MODEL, D_MODEL, D_MODEL, D_FFN, false, false>
            <<<dim3(D_FFN / 256, RB / 256, 1), 512, 0, stream>>>(
                x_hi + aoff, x_lo + aoff, x_hi + aoff,
                wT_a, wT_a, wT_b, Eblk);
        topk256<<<RB, 256, 0, stream>>>(
            Eblk, x + aoff, wg,
            idx + (size_t)rb * RB * TOPK, gk + (size_t)rb * RB * TOPK);
    }

    // 3) weight conversions for U/down phases (wg copies dead now)
    transpose_bf16<false><<<dim3(D_FFN / 32, D_MODEL / 32), 256, 0, stream>>>(
        wu, wT_a, nullptr, D_MODEL, D_FFN);   // wuT [D_FFN][D_MODEL]
    transpose_bf16<false><<<dim3(D_MODEL / 32, D_FFN / 32), 256, 0, stream>>>(
        wd, wT_b, nullptr, D_FFN, D_MODEL);   // wdT [D_MODEL][D_FFN]

    if (fullZd) {
        // 4a) U (bf16 out) -> fused zero+scatter into full Zd, per row-block
        for (int rb = 0; rb < NRB; ++rb) {
            const size_t aoff = (size_t)rb * RB * D_MODEL;
            g256p<1, D_MODEL, D_MODEL, D_MODEL, D_FFN, false, true>
                <<<dim3(D_FFN / 256, RB / 256, 1), 512, 0, stream>>>(
                    x_hi + aoff, nullptr, nullptr, wT_a, nullptr, nullptr, Eblk);
            z_zero_scatter<<<RB, 256, 0, stream>>>(
                idx + (size_t)rb * RB * TOPK, gk + (size_t)rb * RB * TOPK,
                Ub, Zd_full + (size_t)rb * RB * D_FFN);
        }
        // 5a) single full-K down projection, no atomics
        g256p<1, D_FFN, D_FFN, D_FFN, D_MODEL, false, false>
            <<<dim3(D_MODEL / 256, NTOK / 256, 1), 512, 0, stream>>>(
                Zd_full, nullptr, nullptr, wT_b, nullptr, nullptr, out);
    } else {
        // 4b) fallback (r12-proven): per-rb Zd + k-split atomic down
        zero_buf<<<4096, 256, 0, stream>>>(
            (float4*)out, (int)((size_t)NTOK * D_MODEL * 4 / 16));
        for (int rb = 0; rb < NRB; ++rb) {
            const size_t aoff = (size_t)rb * RB * D_MODEL;
            g256p<1, D_MODEL, D_MODEL, D_MODEL, D_FFN, false, true>
                <<<dim3(D_FFN / 256, RB / 256, 1), 512, 0, stream>>>(
                    x_hi + aoff, nullptr, nullptr, wT_a, nullptr, nullptr, Eblk);
            z_zero_scatter<<<RB, 256, 0, stream>>>(
                idx + (size_t)rb * RB * TOPK, gk + (size_t)rb * RB * TOPK,
                Ub, Zdb);
            g256p<1, D_MODEL, D_FFN, D_FFN, D_MODEL, true, false>
                <<<dim3(D_MODEL / 256, RB / 256, D_FFN / D_MODEL), 512, 0, stream>>>(
                    Zdb, nullptr, nullptr, wT_b, nullptr, nullptr, out + aoff);
        }
    }
}

// Round 18
// 2091.956 us; speedup vs baseline: 1.0060x; 1.0048x over previous
//
#include <hip/hip_runtime.h>
#include <hip/hip_bf16.h>
#include <stdint.h>

#define D_MODEL 2048
#define D_FFN   8192
#define NTOK    8192
#define TOPK    256

typedef __bf16 bf16x8 __attribute__((ext_vector_type(8)));
typedef __bf16 bf16x4 __attribute__((ext_vector_type(4)));
typedef float  f32x4  __attribute__((ext_vector_type(4)));

// ---------------------------------------------------------------------------
// global -> LDS direct (16B per lane; LDS dest = wave-uniform base + lane*16)
// ---------------------------------------------------------------------------
__device__ inline void load_lds16(const void* g, void* l) {
    __builtin_amdgcn_global_load_lds((__attribute__((address_space(1))) void*)g,
                                     (__attribute__((address_space(3))) void*)l,
                                     16, 0, 0);
}

// ===========================================================================
// 256x256 bf16 GEMM — K-half slot ring, 4 slot-phases/iter, TWO barriers per
// slot-phase (r12-verified schedule), MFMA 16x16x32 (r14-verified layout),
// + XCD-chunked block swizzle.
// LESSON LEDGER:
//  r4/r5  — under waves_per_eu(2)'s 256-reg budget the accumulator spills:
//           3.8 GB scratch, 6.8% MfmaUtil.
//  r11    — sparse gather-refine loses to dense MFMA correction.
//  r13    — the phase-OPEN barrier is load-bearing (phase-aligns the 2
//           waves/SIMD). Removing it cost 7%. Do NOT remove.
//  r15/16 — 32x32x16 MFMA reads (32 rows x 2 lanes/row) carry a fixed
//           +4 cyc/b128 LDS penalty INVARIANT to chunk-XOR choice; the
//           16x16x32 pattern is conflict-free. 32x32 loses net.
//  r17    — swizzle keys must match EXACTLY on both sides (rule 21): staging
//           key (sr0>>1)&3 must equal read key (fr>>1)&3 on row bits 1-2.
//           Pasting the 32x32 key ((r>>1)^(r>>3)) on one side only => 3/4 of
//           rows read the wrong K-chunk => absmax 0.2. Diff against the last
//           PASSING source when reverting, not against memory.
// Fragment layout (16x16x32): A/B row = lane&15, k = (lane>>4)*8+e;
// C/D col = lane&15, row = (lane>>4)*4 + reg  [m89-verified].
// Ring invariants (r8/r9): one A+B K-half staged per slot-phase landing 6
// phases before first read; vmcnt(4) at sp1/sp3 close (vm(0) last iter)
// retires exactly the two slots read next.
// XCD swizzle: bijective chunked remap (xy-grid % 8 == 0 at all call sites).
// ===========================================================================
template<int NSEG, int SEGK, int LDA, int LDB, int LDC, bool ATOMIC, bool OUTB16>
__global__ __attribute__((amdgpu_flat_work_group_size(512, 512),
                          amdgpu_waves_per_eu(2)))
void g256p(const __bf16* __restrict__ A0, const __bf16* __restrict__ A1,
           const __bf16* __restrict__ A2,
           const __bf16* __restrict__ B0, const __bf16* __restrict__ B1,
           const __bf16* __restrict__ B2,
           float* __restrict__ C)
{
    constexpr int KEXT = NSEG * SEGK;  // K extent per block
    constexpr int NH   = KEXT / 32;    // K-halves
    constexpr int NIT  = NH / 4;       // ring iterations

    __shared__ __align__(16) __bf16 sA[4][256][32];   // 64 KiB
    __shared__ __align__(16) __bf16 sB[4][256][32];   // 64 KiB

    const int tid  = threadIdx.x;
    const int lane = tid & 63;
    const int wid  = tid >> 6;            // 0..7

    // XCD-chunked bijective block swizzle (xy-grid size is a multiple of 8)
    const int bid0 = blockIdx.y * gridDim.x + blockIdx.x;
    const int nbl  = gridDim.x * gridDim.y;
    const int bid  = (bid0 & 7) * (nbl >> 3) + (bid0 >> 3);
    const int mb   = bid / gridDim.x;
    const int nb   = bid - mb * gridDim.x;

    const size_t zoff = (size_t)blockIdx.z * KEXT;   // k-split (gridDim.z>1 => NSEG==1)
    A0 += zoff; B0 += zoff;

    const int wm = (wid >> 2) * 128;      // wave A-rows [wm, wm+128)
    const int wn = (wid & 3) * 64;        // wave B-rows [wn, wn+64)
    const int fr = lane & 15;
    const int q  = lane >> 4;             // 0..3

    // per-lane constant swizzles (rule 21 — r14-verified key on BOTH sides:
    // key(r) = (r>>1)&3, identical for read rows (fr) and staging rows (sr0,
    // both passes: +16 leaves bits 1-2 unchanged))
    const int swz8 = ((q ^ ((fr >> 1) & 3)) * 8);
    const int cl   = lane & 3;
    const int sr0  = wid * 32 + (lane >> 2);
    const int cgel = (cl ^ ((sr0 >> 1) & 3)) * 8;

    f32x4 acc[8][4] = {};

    auto STAGE = [&](int op, int J) {
        const int s = J & 3;
        int seg = 0, kin = J * 32;
        if (NSEG > 1) { seg = (J * 32) / SEGK; kin = J * 32 - seg * SEGK; }
        const __bf16* base = op
            ? ((NSEG == 1 || seg == 0) ? B0 : (seg == 1 ? B1 : B2))
            : ((NSEG == 1 || seg == 0) ? A0 : (seg == 1 ? A1 : A2));
        const int rowbase = (op ? nb : mb) * 256;
        const int ld = op ? LDB : LDA;
        char* ldsb = (char*)(op ? &sB[s][0][0] : &sA[s][0][0]) + wid * 2048;
        #pragma unroll
        for (int p = 0; p < 2; ++p) {
            const int r = sr0 + p * 16;
            load_lds16(base + (size_t)(rowbase + r) * ld + kin + cgel,
                       ldsb + p * 1024);
        }
    };

#define P_READ_B(s) { _Pragma("unroll") for (int ni = 0; ni < 4; ++ni) {       \
        const int r = wn + fr + ni * 16;                                       \
        bfr[ni] = *(const bf16x8*)&sB[s][r][swz8]; } }
#define P_READ_A(s, h) { _Pragma("unroll") for (int mi = 0; mi < 4; ++mi) {    \
        const int r = wm + (h) * 64 + fr + mi * 16;                            \
        af[mi] = *(const bf16x8*)&sA[s][r][swz8]; } }
#define P_MFMA(h) { __builtin_amdgcn_s_setprio(1);                             \
    _Pragma("unroll") for (int mi = 0; mi < 4; ++mi)                           \
    _Pragma("unroll") for (int ni = 0; ni < 4; ++ni)                           \
        acc[(h) * 4 + mi][ni] = __builtin_amdgcn_mfma_f32_16x16x32_bf16(       \
            af[mi], bfr[ni], acc[(h) * 4 + mi][ni], 0, 0, 0);                  \
    __builtin_amdgcn_s_setprio(0); }
#define P_STAGE2(Joff) { const int J = J0 + (Joff);                            \
        if (J >= 4 && J < NH) { STAGE(0, J); STAGE(1, J); } }
#define P_BAR  __builtin_amdgcn_s_barrier()
#define P_LGKM { asm volatile("s_waitcnt lgkmcnt(0)" ::: "memory");            \
                 __builtin_amdgcn_sched_barrier(0); }
// r12 slot-phase: reads+stage, OPEN BAR (phase-aligns waves — r13 lesson),
// lgkm, MFMA h0, read A h1, lgkm, MFMA h1, [vm], CLOSE BAR.
#define SLOT_PHASE(sp, VM) {                                                   \
        P_READ_B(sp); P_READ_A(sp, 0);                                         \
        P_STAGE2(3 + (sp));                                                    \
        P_BAR; P_LGKM;                                                         \
        P_MFMA(0);                                                             \
        __builtin_amdgcn_sched_barrier(0);                                     \
        P_READ_A(sp, 1);                                                       \
        P_LGKM;                                                                \
        P_MFMA(1);                                                             \
        VM;                                                                    \
        P_BAR; }

    #pragma unroll
    for (int J = 0; J < 4; ++J) { STAGE(0, J); STAGE(1, J); }
    asm volatile("s_waitcnt vmcnt(0)" ::: "memory");
    P_BAR;

    for (int i = 0; i < NIT; ++i) {
        const int J0 = 4 * i;
        const bool last = (i == NIT - 1);
        bf16x8 af[4], bfr[4];

        SLOT_PHASE(0, );
        SLOT_PHASE(1,
            if (last) { asm volatile("s_waitcnt vmcnt(0)" ::: "memory"); }
            else      { asm volatile("s_waitcnt vmcnt(4)" ::: "memory"); });
        SLOT_PHASE(2, );
        SLOT_PHASE(3,
            if (last) { asm volatile("s_waitcnt vmcnt(0)" ::: "memory"); }
            else      { asm volatile("s_waitcnt vmcnt(4)" ::: "memory"); });
    }

#undef P_READ_B
#undef P_READ_A
#undef P_MFMA
#undef P_STAGE2
#undef P_BAR
#undef P_LGKM
#undef SLOT_PHASE

    // epilogue: C/D layout col = lane&15, row = (lane>>4)*4 + reg
    const int orow = q * 4;
    #pragma unroll
    for (int ai = 0; ai < 8; ++ai) {
        const int rl = wm + (ai >> 2) * 64 + (ai & 3) * 16 + orow;
        #pragma unroll
        for (int ni = 0; ni < 4; ++ni)
            #pragma unroll
            for (int j = 0; j < 4; ++j) {
                const int r = mb * 256 + rl + j;
                const int c = nb * 256 + wn + ni * 16 + fr;
                const float v = acc[ai][ni][j];
                if (ATOMIC)
                    unsafeAtomicAdd(&C[(size_t)r * LDC + c], v);
                else if (OUTB16)
                    ((__bf16*)C)[(size_t)r * LDC + c] = (__bf16)v;
                else
                    C[(size_t)r * LDC + c] = v;
            }
    }
}

// ---------------------------------------------------------------------------
// x -> (x_hi, x_lo) bf16 split, elementwise
// ---------------------------------------------------------------------------
__global__ __launch_bounds__(256)
void split_convert(const float* __restrict__ in, __bf16* __restrict__ hi,
                   __bf16* __restrict__ lo, int n4)
{
    const int i = blockIdx.x * 256 + threadIdx.x;
    if (i >= n4) return;
    const float4 v = ((const float4*)in)[i];
    float f[4] = {v.x, v.y, v.z, v.w};
    bf16x4 h, l;
    #pragma unroll
    for (int j = 0; j < 4; ++j) {
        __bf16 hb = (__bf16)f[j];
        h[j] = hb;
        l[j] = (__bf16)(f[j] - (float)hb);
    }
    ((bf16x4*)hi)[i] = h;
    ((bf16x4*)lo)[i] = l;
}

// ---------------------------------------------------------------------------
// fp32 [R][C] -> bf16 transposed [C][R] (optionally hi+lo split)
// ---------------------------------------------------------------------------
template<bool SPLIT>
__global__ __launch_bounds__(256)
void transpose_bf16(const float* __restrict__ in, __bf16* __restrict__ outHi,
                    __bf16* __restrict__ outLo, int R, int C)
{
    __shared__ float tile[32][33];
    const int bx = blockIdx.x * 32;
    const int by = blockIdx.y * 32;
    const int tx = threadIdx.x & 31;
    const int ty = threadIdx.x >> 5;
    #pragma unroll
    for (int i = 0; i < 4; ++i)
        tile[ty + 8 * i][tx] = in[(size_t)(by + ty + 8 * i) * C + (bx + tx)];
    __syncthreads();
    #pragma unroll
    for (int i = 0; i < 4; ++i) {
        const float v = tile[tx][ty + 8 * i];
        const size_t o = (size_t)(bx + ty + 8 * i) * R + (by + tx);
        const __bf16 h = (__bf16)v;
        outHi[o] = h;
        if (SPLIT) outLo[o] = (__bf16)(v - (float)h);
    }
}

// ---------------------------------------------------------------------------
// exact top-256 per row of G[rows][D_FFN] fp32 (3-seg GEMM, G err ~1e-6):
// radix-select pivot, then fp64-exact arbitration of the ambiguous boundary
// (|g - vT| <= EPS) using the ORIGINAL fp32 x row and w_gate columns.
// Proven r3-r9/r12/r14. (r11: dense correction GEMM beats gather-refine.)
// ---------------------------------------------------------------------------
#define TK_EPS 3e-5f
#define TK_MAXA 64

__global__ __launch_bounds__(256)
void topk256(const float* __restrict__ G, const float* __restrict__ xblk,
             const float* __restrict__ wgate,
             int* __restrict__ idxOut, float* __restrict__ gkOut)
{
    const int row = blockIdx.x;
    const int t = threadIdx.x;
    const int lane = t & 63;
    const int wid  = t >> 6;

    __shared__ unsigned keys[D_FFN];
    __shared__ float    xr[D_MODEL];
    __shared__ unsigned hist[256];
    __shared__ unsigned scanb[256];
    __shared__ int      sIdx[TOPK];
    __shared__ float    sVal[TOPK];
    __shared__ int      ambIdx[TK_MAXA];
    __shared__ double   ambVal[TK_MAXA];
    __shared__ double   redW[4];
    __shared__ unsigned sh_bin, sh_above, sh_nc, sh_na, sh_fill;

    const float* g = G + (size_t)row * D_FFN;
    const float* xrow = xblk + (size_t)row * D_MODEL;
    for (int i = t; i < D_FFN; i += 256) {
        const unsigned u = __float_as_uint(g[i]);
        keys[i] = (u & 0x80000000u) ? ~u : (u | 0x80000000u);
    }
    for (int i = t; i < D_MODEL; i += 256) xr[i] = xrow[i];
    if (t == 0) { sh_nc = 0; sh_na = 0; sh_fill = 0; }
    __syncthreads();

    unsigned prefix = 0, pmask = 0;
    int remaining = TOPK;
    for (int shift = 24; shift >= 0; shift -= 8) {
        hist[t] = 0;
        __syncthreads();
        for (int i = t; i < D_FFN; i += 256) {
            const unsigned k = keys[i];
            if ((k & pmask) == prefix) atomicAdd(&hist[(k >> shift) & 255u], 1u);
        }
        __syncthreads();
        scanb[t] = hist[t];
        __syncthreads();
        for (int off = 1; off < 256; off <<= 1) {
            const unsigned add = (t + off < 256) ? scanb[t + off] : 0u;
            __syncthreads();
            scanb[t] += add;
            __syncthreads();
        }
        const unsigned above = (t == 255) ? 0u : scanb[t + 1];
        if (scanb[t] >= (unsigned)remaining && above < (unsigned)remaining) {
            sh_bin = (unsigned)t;
            sh_above = above;
        }
        __syncthreads();
        prefix |= sh_bin << shift;
        pmask  |= 0xFFu << shift;
        remaining -= (int)sh_above;
        __syncthreads();
    }
    const unsigned Tkey = prefix;
    const float vT = __uint_as_float((Tkey & 0x80000000u) ? (Tkey & 0x7FFFFFFFu) : ~Tkey);

    for (int i = t; i < D_FFN; i += 256) {
        const unsigned k = keys[i];
        const float f = __uint_as_float((k & 0x80000000u) ? (k & 0x7FFFFFFFu) : ~k);
        if (f > vT + TK_EPS) {
            const unsigned p = atomicAdd(&sh_nc, 1u);
            sIdx[p] = i;
            sVal[p] = f;
        } else if (f >= vT - TK_EPS) {
            const unsigned p = atomicAdd(&sh_na, 1u);
            if (p < TK_MAXA) ambIdx[p] = i;
        }
    }
    __syncthreads();
    const int nc = (int)sh_nc;
    const int na = min((int)sh_na, TK_MAXA);
    const int need = TOPK - nc;

    if (need >= na) {
        if (t < na) {
            const unsigned k = keys[ambIdx[t]];
            sIdx[nc + t] = ambIdx[t];
            sVal[nc + t] = __uint_as_float((k & 0x80000000u) ? (k & 0x7FFFFFFFu) : ~k);
        }
        __syncthreads();
    } else {
        for (int j = 0; j < na; ++j) {
            const int col = ambIdx[j];
            double p = 0.0;
            for (int k = t; k < D_MODEL; k += 256)
                p += (double)xr[k] * (double)wgate[(size_t)k * D_FFN + col];
            #pragma unroll
            for (int o = 32; o > 0; o >>= 1) p += __shfl_xor(p, o, 64);
            if (lane == 0) redW[wid] = p;
            __syncthreads();
            if (t == 0) ambVal[j] = (redW[0] + redW[1]) + (redW[2] + redW[3]);
            __syncthreads();
        }
        if (t < na) {
            const double v = ambVal[t];
            const int    c = ambIdx[t];
            int r = 0;
            for (int j = 0; j < na; ++j) {
                const double vj = ambVal[j];
                if (vj > v || (vj == v && ambIdx[j] < c)) r++;
            }
            if (r < need) {
                const unsigned p = atomicAdd(&sh_fill, 1u);
                sIdx[nc + p] = c;
                sVal[nc + p] = (float)v;
            }
        }
        __syncthreads();
    }

    idxOut[(size_t)row * TOPK + t] = sIdx[t];
    gkOut[(size_t)row * TOPK + t] = sVal[t];
}

// ---------------------------------------------------------------------------
// per-row: zero the Zd row, then scatter z = silu(gk)*u at the 256 selected
// columns (U stored bf16). Replaces zero_buf + z_fused (launch fusion).
// ---------------------------------------------------------------------------
__global__ __launch_bounds__(256)
void z_zero_scatter(const int* __restrict__ idx, const float* __restrict__ gk,
                    const __bf16* __restrict__ Ub, __bf16* __restrict__ Zd)
{
    const int r = blockIdx.x, t = threadIdx.x;
    bf16x8 zv = {};
    bf16x8* rowv = (bf16x8*)(Zd + (size_t)r * D_FFN);
    #pragma unroll
    for (int j = 0; j < 4; ++j) rowv[j * 256 + t] = zv;   // 8192 bf16 zeroed
    __syncthreads();
    const int p = r * TOPK + t;
    const int c = idx[p];
    const float g = gk[p];
    const float u = (float)Ub[(size_t)r * D_FFN + c];
    const float s = g / (1.0f + __expf(-g));
    Zd[(size_t)r * D_FFN + c] = (__bf16)(s * u);
}

__global__ __launch_bounds__(256)
void zero_buf(float4* __restrict__ p, int n)
{
    int i = blockIdx.x * 256 + threadIdx.x;
    const int stride = gridDim.x * 256;
    for (; i < n; i += stride) p[i] = make_float4(0.f, 0.f, 0.f, 0.f);
}

// ---------------------------------------------------------------------------
extern "C" void kernel_launch(void* const* d_in, const int* in_sizes, int n_in,
                              void* d_out, int out_size, void* d_ws, size_t ws_size,
                              hipStream_t stream)
{
    const float* x  = (const float*)d_in[0];
    const float* wg = (const float*)d_in[1];
    const float* wu = (const float*)d_in[2];
    const float* wd = (const float*)d_in[3];
    float* out = (float*)d_out;

    const size_t SZ_XB = (size_t)NTOK * D_MODEL * 2;    // 32 MiB
    const size_t SZ_WB = (size_t)D_FFN * D_MODEL * 2;   // 32 MiB
    const size_t SZ_IK = (size_t)NTOK * TOPK * 4;       // 8 MiB
    const size_t SZ_ZD = (size_t)NTOK * D_FFN * 2;      // 128 MiB (full Zd)
    char* ws = (char*)d_ws;
    size_t off = 0;
    auto alloc = [&](size_t bytes) -> char* {
        char* p = ws + off;
        off += (bytes + 255) & ~(size_t)255;
        return p;
    };
    __bf16* x_hi  = (__bf16*)alloc(SZ_XB);
    __bf16* wT_a  = (__bf16*)alloc(SZ_WB);   // wgT_hi, then wuT
    __bf16* wT_b  = (__bf16*)alloc(SZ_WB);   // wgT_lo, then wdT
    int*    idx   = (int*)  alloc(SZ_IK);
    float*  gk    = (float*)alloc(SZ_IK);

    // row-block size: Eblk (fp32 RB x D_FFN) + x_lo must fit
    int RB = 2048;
    while (RB > 256 && off + (size_t)RB * D_FFN * 4 + SZ_XB > ws_size) RB >>= 1;
    float*  Eblk = (float*)alloc((size_t)RB * D_FFN * 4);  // G fp32, then U bf16
    const size_t xlo_off = off;
    __bf16* x_lo = (__bf16*)alloc(SZ_XB);
    // full-Zd fast path: Zd overlays x_lo (dead after G phase) + extension
    const bool fullZd = (RB == 2048) && (xlo_off + SZ_ZD <= ws_size);
    __bf16* Zd_full = (__bf16*)(ws + xlo_off);
    __bf16* Zdb     = x_lo;                                // fallback per-rb Zd
    __bf16* Ub      = (__bf16*)Eblk;                       // U stored bf16
    const int NRB = NTOK / RB;

    // 1) operand conversions for the G phase
    split_convert<<<(NTOK * D_MODEL / 4 + 255) / 256, 256, 0, stream>>>(
        x, x_hi, x_lo, NTOK * D_MODEL / 4);
    transpose_bf16<true><<<dim3(D_FFN / 32, D_MODEL / 32), 256, 0, stream>>>(
        wg, wT_a, wT_b, D_MODEL, D_FFN);   // wgT_hi, wgT_lo

    // 2) G phase per row-block: 3-seg stacked-K bf16 GEMM -> exact topk
    for (int rb = 0; rb < NRB; ++rb) {
        const size_t aoff = (size_t)rb * RB * D_MODEL;
        g256p<3, D_MODEL, D_MODEL, D_MODEL, D_FFN, false, false>
            <<<dim3(D_FFN / 256, RB / 256, 1), 512, 0, stream>>>(
                x_hi + aoff, x_lo + aoff, x_hi + aoff,
                wT_a, wT_a, wT_b, Eblk);
        topk256<<<RB, 256, 0, stream>>>(
            Eblk, x + aoff, wg,
            idx + (size_t)rb * RB * TOPK, gk + (size_t)rb * RB * TOPK);
    }

    // 3) weight conversions for U/down phases (wg copies dead now)
    transpose_bf16<false><<<dim3(D_FFN / 32, D_MODEL / 32), 256, 0, stream>>>(
        wu, wT_a, nullptr, D_MODEL, D_FFN);   // wuT [D_FFN][D_MODEL]
    transpose_bf16<false><<<dim3(D_MODEL / 32, D_FFN / 32), 256, 0, stream>>>(
        wd, wT_b, nullptr, D_FFN, D_MODEL);   // wdT [D_MODEL][D_FFN]

    if (fullZd) {
        // 4a) U (bf16 out) -> fused zero+scatter into full Zd, per row-block
        for (int rb = 0; rb < NRB; ++rb) {
            const size_t aoff = (size_t)rb * RB * D_MODEL;
            g256p<1, D_MODEL, D_MODEL, D_MODEL, D_FFN, false, true>
                <<<dim3(D_FFN / 256, RB / 256, 1), 512, 0, stream>>>(
                    x_hi + aoff, nullptr, nullptr, wT_a, nullptr, nullptr, Eblk);
            z_zero_scatter<<<RB, 256, 0, stream>>>(
                idx + (size_t)rb * RB * TOPK, gk + (size_t)rb * RB * TOPK,
                Ub, Zd_full + (size_t)rb * RB * D_FFN);
        }
        // 5a) single full-K down projection, no atomics
        g256p<1, D_FFN, D_FFN, D_FFN, D_MODEL, false, false>
            <<<dim3(D_MODEL / 256, NTOK / 256, 1), 512, 0, stream>>>(
                Zd_full, nullptr, nullptr, wT_b, nullptr, nullptr, out);
    } else {
        // 4b) fallback (r12-proven): per-rb Zd + k-split atomic down
        zero_buf<<<4096, 256, 0, stream>>>(
            (float4*)out, (int)((size_t)NTOK * D_MODEL * 4 / 16));
        for (int rb = 0; rb < NRB; ++rb) {
            const size_t aoff = (size_t)rb * RB * D_MODEL;
            g256p<1, D_MODEL, D_MODEL, D_MODEL, D_FFN, false, true>
                <<<dim3(D_FFN / 256, RB / 256, 1), 512, 0, stream>>>(
                    x_hi + aoff, nullptr, nullptr, wT_a, nullptr, nullptr, Eblk);
            z_zero_scatter<<<RB, 256, 0, stream>>>(
                idx + (size_t)rb * RB * TOPK, gk + (size_t)rb * RB * TOPK,
                Ub, Zdb);
            g256p<1, D_MODEL, D_FFN, D_FFN, D_MODEL, true, false>
                <<<dim3(D_MODEL / 256, RB / 256, D_FFN / D_MODEL), 512, 0, stream>>>(
                    Zdb, nullptr, nullptr, wT_b, nullptr, nullptr, out + aoff);
        }
    }
}

// Round 19
// 2044.142 us; speedup vs baseline: 1.0295x; 1.0234x over previous
//
#include <hip/hip_runtime.h>
#include <hip/hip_bf16.h>
#include <stdint.h>

#define D_MODEL 2048
#define D_FFN   8192
#define NTOK    8192
#define TOPK    256

typedef __bf16 bf16x8 __attribute__((ext_vector_type(8)));
typedef __bf16 bf16x4 __attribute__((ext_vector_type(4)));
typedef float  f32x4  __attribute__((ext_vector_type(4)));

// ---------------------------------------------------------------------------
// global -> LDS direct (16B per lane; LDS dest = wave-uniform base + lane*16)
// ---------------------------------------------------------------------------
__device__ inline void load_lds16(const void* g, void* l) {
    __builtin_amdgcn_global_load_lds((__attribute__((address_space(1))) void*)g,
                                     (__attribute__((address_space(3))) void*)l,
                                     16, 0, 0);
}

// ===========================================================================
// 256x256 bf16 GEMM — K-half slot ring, 4 slot-phases/iter, TWO barriers per
// slot-phase (r12-verified schedule), MFMA 16x16x32 (r14-verified layout).
// LESSON LEDGER:
//  r4/r5  — under waves_per_eu(2)'s 256-reg budget the accumulator spills:
//           3.8 GB scratch, 6.8% MfmaUtil.
//  r11    — sparse gather-refine loses to dense MFMA correction.
//  r13    — the phase-OPEN barrier is load-bearing (phase-aligns the 2
//           waves/SIMD). Removing it cost 7%. Do NOT remove.
//  r15/16 — 32x32x16 MFMA reads carry a fixed +4 cyc/b128 LDS penalty
//           invariant to chunk-XOR; 16x16x32 pattern is conflict-free.
//  r17    — swizzle keys must match EXACTLY on both sides (rule 21); diff
//           against the last PASSING source when reverting.
//  r18    — XCD-chunked block swizzle TRIPLED HBM fetch (147->406 MB): the
//           default dispatch mapping already has the better L2/L3 reuse
//           here. Do NOT remap blockIdx for this grid shape.
// Fragment layout (16x16x32): A/B row = lane&15, k = (lane>>4)*8+e;
// C/D col = lane&15, row = (lane>>4)*4 + reg  [m89-verified].
// Ring invariants (r8/r9): one A+B K-half staged per slot-phase landing 6
// phases before first read; vmcnt(4) at sp1/sp3 close (vm(0) last iter)
// retires exactly the two slots read next.
// ===========================================================================
template<int NSEG, int SEGK, int LDA, int LDB, int LDC, bool ATOMIC, bool OUTB16>
__global__ __attribute__((amdgpu_flat_work_group_size(512, 512),
                          amdgpu_waves_per_eu(2)))
void g256p(const __bf16* __restrict__ A0, const __bf16* __restrict__ A1,
           const __bf16* __restrict__ A2,
           const __bf16* __restrict__ B0, const __bf16* __restrict__ B1,
           const __bf16* __restrict__ B2,
           float* __restrict__ C)
{
    constexpr int KEXT = NSEG * SEGK;  // K extent per block
    constexpr int NH   = KEXT / 32;    // K-halves
    constexpr int NIT  = NH / 4;       // ring iterations

    __shared__ __align__(16) __bf16 sA[4][256][32];   // 64 KiB
    __shared__ __align__(16) __bf16 sB[4][256][32];   // 64 KiB

    const int tid  = threadIdx.x;
    const int lane = tid & 63;
    const int wid  = tid >> 6;            // 0..7
    const int mb   = blockIdx.y;          // r18 lesson: default mapping wins
    const int nb   = blockIdx.x;

    const size_t zoff = (size_t)blockIdx.z * KEXT;   // k-split (gridDim.z>1 => NSEG==1)
    A0 += zoff; B0 += zoff;

    const int wm = (wid >> 2) * 128;      // wave A-rows [wm, wm+128)
    const int wn = (wid & 3) * 64;        // wave B-rows [wn, wn+64)
    const int fr = lane & 15;
    const int q  = lane >> 4;             // 0..3

    // per-lane constant swizzles (rule 21 — same key(r) = (r>>1)&3 on BOTH
    // sides; staging rows sr0/+16 leave bits 1-2 unchanged)
    const int swz8 = ((q ^ ((fr >> 1) & 3)) * 8);
    const int cl   = lane & 3;
    const int sr0  = wid * 32 + (lane >> 2);
    const int cgel = (cl ^ ((sr0 >> 1) & 3)) * 8;

    f32x4 acc[8][4] = {};

    auto STAGE = [&](int op, int J) {
        const int s = J & 3;
        int seg = 0, kin = J * 32;
        if (NSEG > 1) { seg = (J * 32) / SEGK; kin = J * 32 - seg * SEGK; }
        const __bf16* base = op
            ? ((NSEG == 1 || seg == 0) ? B0 : (seg == 1 ? B1 : B2))
            : ((NSEG == 1 || seg == 0) ? A0 : (seg == 1 ? A1 : A2));
        const int rowbase = (op ? nb : mb) * 256;
        const int ld = op ? LDB : LDA;
        char* ldsb = (char*)(op ? &sB[s][0][0] : &sA[s][0][0]) + wid * 2048;
        #pragma unroll
        for (int p = 0; p < 2; ++p) {
            const int r = sr0 + p * 16;
            load_lds16(base + (size_t)(rowbase + r) * ld + kin + cgel,
                       ldsb + p * 1024);
        }
    };

#define P_READ_B(s) { _Pragma("unroll") for (int ni = 0; ni < 4; ++ni) {       \
        const int r = wn + fr + ni * 16;                                       \
        bfr[ni] = *(const bf16x8*)&sB[s][r][swz8]; } }
#define P_READ_A(s, h) { _Pragma("unroll") for (int mi = 0; mi < 4; ++mi) {    \
        const int r = wm + (h) * 64 + fr + mi * 16;                            \
        af[mi] = *(const bf16x8*)&sA[s][r][swz8]; } }
#define P_MFMA(h) { __builtin_amdgcn_s_setprio(1);                             \
    _Pragma("unroll") for (int mi = 0; mi < 4; ++mi)                           \
    _Pragma("unroll") for (int ni = 0; ni < 4; ++ni)                           \
        acc[(h) * 4 + mi][ni] = __builtin_amdgcn_mfma_f32_16x16x32_bf16(       \
            af[mi], bfr[ni], acc[(h) * 4 + mi][ni], 0, 0, 0);                  \
    __builtin_amdgcn_s_setprio(0); }
#define P_STAGE2(Joff) { const int J = J0 + (Joff);                            \
        if (J >= 4 && J < NH) { STAGE(0, J); STAGE(1, J); } }
#define P_BAR  __builtin_amdgcn_s_barrier()
#define P_LGKM { asm volatile("s_waitcnt lgkmcnt(0)" ::: "memory");            \
                 __builtin_amdgcn_sched_barrier(0); }
// r12 slot-phase: reads+stage, OPEN BAR (phase-aligns waves — r13 lesson),
// lgkm, MFMA h0, read A h1, lgkm, MFMA h1, [vm], CLOSE BAR.
#define SLOT_PHASE(sp, VM) {                                                   \
        P_READ_B(sp); P_READ_A(sp, 0);                                         \
        P_STAGE2(3 + (sp));                                                    \
        P_BAR; P_LGKM;                                                         \
        P_MFMA(0);                                                             \
        __builtin_amdgcn_sched_barrier(0);                                     \
        P_READ_A(sp, 1);                                                       \
        P_LGKM;                                                                \
        P_MFMA(1);                                                             \
        VM;                                                                    \
        P_BAR; }

    #pragma unroll
    for (int J = 0; J < 4; ++J) { STAGE(0, J); STAGE(1, J); }
    asm volatile("s_waitcnt vmcnt(0)" ::: "memory");
    P_BAR;

    for (int i = 0; i < NIT; ++i) {
        const int J0 = 4 * i;
        const bool last = (i == NIT - 1);
        bf16x8 af[4], bfr[4];

        SLOT_PHASE(0, );
        SLOT_PHASE(1,
            if (last) { asm volatile("s_waitcnt vmcnt(0)" ::: "memory"); }
            else      { asm volatile("s_waitcnt vmcnt(4)" ::: "memory"); });
        SLOT_PHASE(2, );
        SLOT_PHASE(3,
            if (last) { asm volatile("s_waitcnt vmcnt(0)" ::: "memory"); }
            else      { asm volatile("s_waitcnt vmcnt(4)" ::: "memory"); });
    }

#undef P_READ_B
#undef P_READ_A
#undef P_MFMA
#undef P_STAGE2
#undef P_BAR
#undef P_LGKM
#undef SLOT_PHASE

    // epilogue: C/D layout col = lane&15, row = (lane>>4)*4 + reg
    const int orow = q * 4;
    #pragma unroll
    for (int ai = 0; ai < 8; ++ai) {
        const int rl = wm + (ai >> 2) * 64 + (ai & 3) * 16 + orow;
        #pragma unroll
        for (int ni = 0; ni < 4; ++ni)
            #pragma unroll
            for (int j = 0; j < 4; ++j) {
                const int r = mb * 256 + rl + j;
                const int c = nb * 256 + wn + ni * 16 + fr;
                const float v = acc[ai][ni][j];
                if (ATOMIC)
                    unsafeAtomicAdd(&C[(size_t)r * LDC + c], v);
                else if (OUTB16)
                    ((__bf16*)C)[(size_t)r * LDC + c] = (__bf16)v;
                else
                    C[(size_t)r * LDC + c] = v;
            }
    }
}

// ---------------------------------------------------------------------------
// x -> (x_hi, x_lo) bf16 split, elementwise
// ---------------------------------------------------------------------------
__global__ __launch_bounds__(256)
void split_convert(const float* __restrict__ in, __bf16* __restrict__ hi,
                   __bf16* __restrict__ lo, int n4)
{
    const int i = blockIdx.x * 256 + threadIdx.x;
    if (i >= n4) return;
    const float4 v = ((const float4*)in)[i];
    float f[4] = {v.x, v.y, v.z, v.w};
    bf16x4 h, l;
    #pragma unroll
    for (int j = 0; j < 4; ++j) {
        __bf16 hb = (__bf16)f[j];
        h[j] = hb;
        l[j] = (__bf16)(f[j] - (float)hb);
    }
    ((bf16x4*)hi)[i] = h;
    ((bf16x4*)lo)[i] = l;
}

// ---------------------------------------------------------------------------
// fp32 [R][C] -> bf16 transposed [C][R] (optionally hi+lo split)
// ---------------------------------------------------------------------------
template<bool SPLIT>
__global__ __launch_bounds__(256)
void transpose_bf16(const float* __restrict__ in, __bf16* __restrict__ outHi,
                    __bf16* __restrict__ outLo, int R, int C)
{
    __shared__ float tile[32][33];
    const int bx = blockIdx.x * 32;
    const int by = blockIdx.y * 32;
    const int tx = threadIdx.x & 31;
    const int ty = threadIdx.x >> 5;
    #pragma unroll
    for (int i = 0; i < 4; ++i)
        tile[ty + 8 * i][tx] = in[(size_t)(by + ty + 8 * i) * C + (bx + tx)];
    __syncthreads();
    #pragma unroll
    for (int i = 0; i < 4; ++i) {
        const float v = tile[tx][ty + 8 * i];
        const size_t o = (size_t)(bx + ty + 8 * i) * R + (by + tx);
        const __bf16 h = (__bf16)v;
        outHi[o] = h;
        if (SPLIT) outLo[o] = (__bf16)(v - (float)h);
    }
}

// ---------------------------------------------------------------------------
// exact top-256 per row of G[rows][D_FFN] fp32 (3-seg GEMM, G err ~1e-6):
// radix-select pivot, then fp64-exact arbitration of the ambiguous boundary
// (|g - vT| <= EPS) using the ORIGINAL fp32 x row and w_gate columns.
// Proven r3-r9/r12/r14. (r11: dense correction GEMM beats gather-refine.)
// ---------------------------------------------------------------------------
#define TK_EPS 3e-5f
#define TK_MAXA 64

__global__ __launch_bounds__(256)
void topk256(const float* __restrict__ G, const float* __restrict__ xblk,
             const float* __restrict__ wgate,
             int* __restrict__ idxOut, float* __restrict__ gkOut)
{
    const int row = blockIdx.x;
    const int t = threadIdx.x;
    const int lane = t & 63;
    const int wid  = t >> 6;

    __shared__ unsigned keys[D_FFN];
    __shared__ float    xr[D_MODEL];
    __shared__ unsigned hist[256];
    __shared__ unsigned scanb[256];
    __shared__ int      sIdx[TOPK];
    __shared__ float    sVal[TOPK];
    __shared__ int      ambIdx[TK_MAXA];
    __shared__ double   ambVal[TK_MAXA];
    __shared__ double   redW[4];
    __shared__ unsigned sh_bin, sh_above, sh_nc, sh_na, sh_fill;

    const float* g = G + (size_t)row * D_FFN;
    const float* xrow = xblk + (size_t)row * D_MODEL;
    for (int i = t; i < D_FFN; i += 256) {
        const unsigned u = __float_as_uint(g[i]);
        keys[i] = (u & 0x80000000u) ? ~u : (u | 0x80000000u);
    }
    for (int i = t; i < D_MODEL; i += 256) xr[i] = xrow[i];
    if (t == 0) { sh_nc = 0; sh_na = 0; sh_fill = 0; }
    __syncthreads();

    unsigned prefix = 0, pmask = 0;
    int remaining = TOPK;
    for (int shift = 24; shift >= 0; shift -= 8) {
        hist[t] = 0;
        __syncthreads();
        for (int i = t; i < D_FFN; i += 256) {
            const unsigned k = keys[i];
            if ((k & pmask) == prefix) atomicAdd(&hist[(k >> shift) & 255u], 1u);
        }
        __syncthreads();
        scanb[t] = hist[t];
        __syncthreads();
        for (int off = 1; off < 256; off <<= 1) {
            const unsigned add = (t + off < 256) ? scanb[t + off] : 0u;
            __syncthreads();
            scanb[t] += add;
            __syncthreads();
        }
        const unsigned above = (t == 255) ? 0u : scanb[t + 1];
        if (scanb[t] >= (unsigned)remaining && above < (unsigned)remaining) {
            sh_bin = (unsigned)t;
            sh_above = above;
        }
        __syncthreads();
        prefix |= sh_bin << shift;
        pmask  |= 0xFFu << shift;
        remaining -= (int)sh_above;
        __syncthreads();
    }
    const unsigned Tkey = prefix;
    const float vT = __uint_as_float((Tkey & 0x80000000u) ? (Tkey & 0x7FFFFFFFu) : ~Tkey);

    for (int i = t; i < D_FFN; i += 256) {
        const unsigned k = keys[i];
        const float f = __uint_as_float((k & 0x80000000u) ? (k & 0x7FFFFFFFu) : ~k);
        if (f > vT + TK_EPS) {
            const unsigned p = atomicAdd(&sh_nc, 1u);
            sIdx[p] = i;
            sVal[p] = f;
        } else if (f >= vT - TK_EPS) {
            const unsigned p = atomicAdd(&sh_na, 1u);
            if (p < TK_MAXA) ambIdx[p] = i;
        }
    }
    __syncthreads();
    const int nc = (int)sh_nc;
    const int na = min((int)sh_na, TK_MAXA);
    const int need = TOPK - nc;

    if (need >= na) {
        if (t < na) {
            const unsigned k = keys[ambIdx[t]];
            sIdx[nc + t] = ambIdx[t];
            sVal[nc + t] = __uint_as_float((k & 0x80000000u) ? (k & 0x7FFFFFFFu) : ~k);
        }
        __syncthreads();
    } else {
        for (int j = 0; j < na; ++j) {
            const int col = ambIdx[j];
            double p = 0.0;
            for (int k = t; k < D_MODEL; k += 256)
                p += (double)xr[k] * (double)wgate[(size_t)k * D_FFN + col];
            #pragma unroll
            for (int o = 32; o > 0; o >>= 1) p += __shfl_xor(p, o, 64);
            if (lane == 0) redW[wid] = p;
            __syncthreads();
            if (t == 0) ambVal[j] = (redW[0] + redW[1]) + (redW[2] + redW[3]);
            __syncthreads();
        }
        if (t < na) {
            const double v = ambVal[t];
            const int    c = ambIdx[t];
            int r = 0;
            for (int j = 0; j < na; ++j) {
                const double vj = ambVal[j];
                if (vj > v || (vj == v && ambIdx[j] < c)) r++;
            }
            if (r < need) {
                const unsigned p = atomicAdd(&sh_fill, 1u);
                sIdx[nc + p] = c;
                sVal[nc + p] = (float)v;
            }
        }
        __syncthreads();
    }

    idxOut[(size_t)row * TOPK + t] = sIdx[t];
    gkOut[(size_t)row * TOPK + t] = sVal[t];
}

// ---------------------------------------------------------------------------
// per-row: zero the Zd row, then scatter z = silu(gk)*u at the 256 selected
// columns (U stored bf16). Replaces zero_buf + z_fused (launch fusion).
// ---------------------------------------------------------------------------
__global__ __launch_bounds__(256)
void z_zero_scatter(const int* __restrict__ idx, const float* __restrict__ gk,
                    const __bf16* __restrict__ Ub, __bf16* __restrict__ Zd)
{
    const int r = blockIdx.x, t = threadIdx.x;
    bf16x8 zv = {};
    bf16x8* rowv = (bf16x8*)(Zd + (size_t)r * D_FFN);
    #pragma unroll
    for (int j = 0; j < 4; ++j) rowv[j * 256 + t] = zv;   // 8192 bf16 zeroed
    __syncthreads();
    const int p = r * TOPK + t;
    const int c = idx[p];
    const float g = gk[p];
    const float u = (float)Ub[(size_t)r * D_FFN + c];
    const float s = g / (1.0f + __expf(-g));
    Zd[(size_t)r * D_FFN + c] = (__bf16)(s * u);
}

__global__ __launch_bounds__(256)
void zero_buf(float4* __restrict__ p, int n)
{
    int i = blockIdx.x * 256 + threadIdx.x;
    const int stride = gridDim.x * 256;
    for (; i < n; i += stride) p[i] = make_float4(0.f, 0.f, 0.f, 0.f);
}

// ---------------------------------------------------------------------------
extern "C" void kernel_launch(void* const* d_in, const int* in_sizes, int n_in,
                              void* d_out, int out_size, void* d_ws, size_t ws_size,
                              hipStream_t stream)
{
    const float* x  = (const float*)d_in[0];
    const float* wg = (const float*)d_in[1];
    const float* wu = (const float*)d_in[2];
    const float* wd = (const float*)d_in[3];
    float* out = (float*)d_out;

    const size_t SZ_XB = (size_t)NTOK * D_MODEL * 2;    // 32 MiB
    const size_t SZ_WB = (size_t)D_FFN * D_MODEL * 2;   // 32 MiB
    const size_t SZ_IK = (size_t)NTOK * TOPK * 4;       // 8 MiB
    const size_t SZ_ZD = (size_t)NTOK * D_FFN * 2;      // 128 MiB (full Zd)
    char* ws = (char*)d_ws;
    size_t off = 0;
    auto alloc = [&](size_t bytes) -> char* {
        char* p = ws + off;
        off += (bytes + 255) & ~(size_t)255;
        return p;
    };
    __bf16* x_hi  = (__bf16*)alloc(SZ_XB);
    __bf16* wT_a  = (__bf16*)alloc(SZ_WB);   // wgT_hi, then wuT
    __bf16* wT_b  = (__bf16*)alloc(SZ_WB);   // wgT_lo, then wdT
    int*    idx   = (int*)  alloc(SZ_IK);
    float*  gk    = (float*)alloc(SZ_IK);

    // row-block size: Eblk (fp32 RB x D_FFN) + x_lo must fit
    int RB = 2048;
    while (RB > 256 && off + (size_t)RB * D_FFN * 4 + SZ_XB > ws_size) RB >>= 1;
    float*  Eblk = (float*)alloc((size_t)RB * D_FFN * 4);  // G fp32, then U bf16
    const size_t xlo_off = off;
    __bf16* x_lo = (__bf16*)alloc(SZ_XB);
    // full-Zd fast path: Zd overlays x_lo (dead after G phase) + extension
    const bool fullZd = (RB == 2048) && (xlo_off + SZ_ZD <= ws_size);
    __bf16* Zd_full = (__bf16*)(ws + xlo_off);
    __bf16* Zdb     = x_lo;                                // fallback per-rb Zd
    __bf16* Ub      = (__bf16*)Eblk;                       // U stored bf16
    const int NRB = NTOK / RB;

    // 1) operand conversions for the G phase
    split_convert<<<(NTOK * D_MODEL / 4 + 255) / 256, 256, 0, stream>>>(
        x, x_hi, x_lo, NTOK * D_MODEL / 4);
    transpose_bf16<true><<<dim3(D_FFN / 32, D_MODEL / 32), 256, 0, stream>>>(
        wg, wT_a, wT_b, D_MODEL, D_FFN);   // wgT_hi, wgT_lo

    // 2) G phase per row-block: 3-seg stacked-K bf16 GEMM -> exact topk
    for (int rb = 0; rb < NRB; ++rb) {
        const size_t aoff = (size_t)rb * RB * D_MODEL;
        g256p<3, D_MODEL, D_MODEL, D_MODEL, D_FFN, false, false>
            <<<dim3(D_FFN / 256, RB / 256, 1), 512, 0, stream>>>(
                x_hi + aoff, x_lo + aoff, x_hi + aoff,
                wT_a, wT_a, wT_b, Eblk);
        topk256<<<RB, 256, 0, stream>>>(
            Eblk, x + aoff, wg,
            idx + (size_t)rb * RB * TOPK, gk + (size_t)rb * RB * TOPK);
    }

    // 3) weight conversions for U/down phases (wg copies dead now)
    transpose_bf16<false><<<dim3(D_FFN / 32, D_MODEL / 32), 256, 0, stream>>>(
        wu, wT_a, nullptr, D_MODEL, D_FFN);   // wuT [D_FFN][D_MODEL]
    transpose_bf16<false><<<dim3(D_MODEL / 32, D_FFN / 32), 256, 0, stream>>>(
        wd, wT_b, nullptr, D_FFN, D_MODEL);   // wdT [D_MODEL][D_FFN]

    if (fullZd) {
        // 4a) U (bf16 out) -> fused zero+scatter into full Zd, per row-block
        for (int rb = 0; rb < NRB; ++rb) {
            const size_t aoff = (size_t)rb * RB * D_MODEL;
            g256p<1, D_MODEL, D_MODEL, D_MODEL, D_FFN, false, true>
                <<<dim3(D_FFN / 256, RB / 256, 1), 512, 0, stream>>>(
                    x_hi + aoff, nullptr, nullptr, wT_a, nullptr, nullptr, Eblk);
            z_zero_scatter<<<RB, 256, 0, stream>>>(
                idx + (size_t)rb * RB * TOPK, gk + (size_t)rb * RB * TOPK,
                Ub, Zd_full + (size_t)rb * RB * D_FFN);
        }
        // 5a) single full-K down projection, no atomics
        g256p<1, D_FFN, D_FFN, D_FFN, D_MODEL, false, false>
            <<<dim3(D_MODEL / 256, NTOK / 256, 1), 512, 0, stream>>>(
                Zd_full, nullptr, nullptr, wT_b, nullptr, nullptr, out);
    } else {
        // 4b) fallback (r12-proven): per-rb Zd + k-split atomic down
        zero_buf<<<4096, 256, 0, stream>>>(
            (float4*)out, (int)((size_t)NTOK * D_MODEL * 4 / 16));
        for (int rb = 0; rb < NRB; ++rb) {
            const size_t aoff = (size_t)rb * RB * D_MODEL;
            g256p<1, D_MODEL, D_MODEL, D_MODEL, D_FFN, false, true>
                <<<dim3(D_FFN / 256, RB / 256, 1), 512, 0, stream>>>(
                    x_hi + aoff, nullptr, nullptr, wT_a, nullptr, nullptr, Eblk);
            z_zero_scatter<<<RB, 256, 0, stream>>>(
                idx + (size_t)rb * RB * TOPK, gk + (size_t)rb * RB * TOPK,
                Ub, Zdb);
            g256p<1, D_MODEL, D_FFN, D_FFN, D_MODEL, true, false>
                <<<dim3(D_MODEL / 256, RB / 256, D_FFN / D_MODEL), 512, 0, stream>>>(
                    Zdb, nullptr, nullptr, wT_b, nullptr, nullptr, out + aoff);
        }
    }
}